// Round 2
// baseline (715.850 us; speedup 1.0000x reference)
//
#include <hip/hip_runtime.h>
#include <hip/hip_bf16.h>
#include <math.h>

// Problem constants
#define N_ROWS 16384
#define N_A    256
#define N_F    2048
#define GAMMA  1.5f
#define BN_EPS 1e-5f

typedef __attribute__((ext_vector_type(8))) short short8;
typedef __attribute__((ext_vector_type(4))) float f32x4;

// ---------------------------------------------------------------------------
// K0: fp32 -> bf16 conversion (4 elements/thread, vectorized) — validated
// ---------------------------------------------------------------------------
__global__ __launch_bounds__(256) void cvt_bf16(const float* __restrict__ in,
                                                unsigned short* __restrict__ out,
                                                int n4) {
    int i = blockIdx.x * 256 + threadIdx.x;
    if (i >= n4) return;
    float4 v = reinterpret_cast<const float4*>(in)[i];
    ushort4 o;
    o.x = __builtin_bit_cast(unsigned short, __float2bfloat16(v.x));
    o.y = __builtin_bit_cast(unsigned short, __float2bfloat16(v.y));
    o.z = __builtin_bit_cast(unsigned short, __float2bfloat16(v.z));
    o.w = __builtin_bit_cast(unsigned short, __float2bfloat16(v.w));
    reinterpret_cast<ushort4*>(out)[i] = o;
}

// ---------------------------------------------------------------------------
// K1: stats-only GEMM. Identical structure + numerics to the VALIDATED gemm_x
// (128x128 tile, acc[2][8], same fragment layout, same s1/s2 reduction and
// deterministic per-blockIdx.y partials) with the x store deleted — x is
// recomputed by K3 instead of round-tripping 128 MB through HBM.
// ---------------------------------------------------------------------------
__global__ __launch_bounds__(256) void gemm_stats(const unsigned short* __restrict__ aB,
                                                  const unsigned short* __restrict__ wB,
                                                  const float* __restrict__ bias,
                                                  float* __restrict__ ps1,
                                                  float* __restrict__ ps2) {
    const int lane = threadIdx.x & 63;
    const int wave = threadIdx.x >> 6;
    const int r16  = lane & 15;
    const int quad = lane >> 4;
    const int col0 = blockIdx.x * 128;
    const int rowB = blockIdx.y * 128;
    const int row0 = rowB + wave * 32;

    f32x4 acc[2][8];
    #pragma unroll
    for (int g = 0; g < 2; ++g)
        #pragma unroll
        for (int t = 0; t < 8; ++t)
            acc[g][t] = (f32x4){0.f, 0.f, 0.f, 0.f};

    const unsigned short* aR0 = aB + (size_t)(row0 + r16) * N_A;
    const unsigned short* aR1 = aR0 + 16 * N_A;
    const unsigned short* wR  = wB + (size_t)(col0 + r16) * N_A;

    #pragma unroll
    for (int ks = 0; ks < 8; ++ks) {
        const int k0 = ks * 32 + quad * 8;
        short8 a0 = *reinterpret_cast<const short8*>(aR0 + k0);
        short8 a1 = *reinterpret_cast<const short8*>(aR1 + k0);
        #pragma unroll
        for (int t = 0; t < 8; ++t) {
            short8 bf = *reinterpret_cast<const short8*>(wR + (size_t)t * 16 * N_A + k0);
            acc[0][t] = __builtin_amdgcn_mfma_f32_16x16x32_bf16(a0, bf, acc[0][t], 0, 0, 0);
            acc[1][t] = __builtin_amdgcn_mfma_f32_16x16x32_bf16(a1, bf, acc[1][t], 0, 0, 0);
        }
    }

    __shared__ float cs1[4][128];
    __shared__ float cs2[4][128];

    #pragma unroll
    for (int t = 0; t < 8; ++t) {
        const float bcol = bias[col0 + t * 16 + r16];
        float s1 = 0.f, s2 = 0.f;
        #pragma unroll
        for (int g = 0; g < 2; ++g) {
            #pragma unroll
            for (int r = 0; r < 4; ++r) {
                float v = acc[g][t][r] + bcol;
                s1 += v;
                s2 += v * v;
            }
        }
        // reduce across the 4 quads (rows) -> per-column sums over 32 rows
        s1 += __shfl_xor(s1, 16); s1 += __shfl_xor(s1, 32);
        s2 += __shfl_xor(s2, 16); s2 += __shfl_xor(s2, 32);
        if (quad == 0) { cs1[wave][t * 16 + r16] = s1; cs2[wave][t * 16 + r16] = s2; }
    }
    __syncthreads();

    if (threadIdx.x < 128) {
        const int c = threadIdx.x;
        float s1 = cs1[0][c] + cs1[1][c] + cs1[2][c] + cs1[3][c];
        float s2 = cs2[0][c] + cs2[1][c] + cs2[2][c] + cs2[3][c];
        ps1[(size_t)blockIdx.y * N_F + col0 + c] = s1;
        ps2[(size_t)blockIdx.y * N_F + col0 + c] = s2;
    }
}

// ---------------------------------------------------------------------------
// K2: finalize BN stats (sum 128 deterministic partials) -> scale/shift
// — VERBATIM validated.
// ---------------------------------------------------------------------------
__global__ __launch_bounds__(256) void finalize_stats(const float* __restrict__ ps1,
                                                      const float* __restrict__ ps2,
                                                      const float* __restrict__ bn_w,
                                                      const float* __restrict__ bn_b,
                                                      float* __restrict__ scale,
                                                      float* __restrict__ shift) {
    const int f = blockIdx.x * 256 + threadIdx.x;
    float s1 = 0.f, s2 = 0.f;
    #pragma unroll 4
    for (int i = 0; i < 128; ++i) {
        s1 += ps1[(size_t)i * N_F + f];
        s2 += ps2[(size_t)i * N_F + f];
    }
    const float inv_n = 1.0f / (float)N_ROWS;
    const float mu  = s1 * inv_n;
    const float var = s2 * inv_n - mu * mu;
    const float sc  = bn_w[f] / sqrtf(var + BN_EPS);
    scale[f] = sc;
    shift[f] = bn_b[f] - mu * sc;
}

// ---------------------------------------------------------------------------
// K3: fused GEMM + BN + sparsemax + prior update. One block = 16 rows x all
// 2048 cols; 8 waves of 64, wave w owns cols [w*256, w*256+256). x never
// touches memory: acc (fp32) + bias -> z in-register, tau via cross-wave
// reduce, outputs written directly. Fragment mapping and sparsemax shortcut
// verbatim from the validated kernel:
//   out elem (row = quad*4+reg, col = t*16+r16); tau = (s+1)/(F-1) when
//   1+(F-1)*max-s > 0, else exact degenerate fallback.
// scale/shift are bitwise-identical to the validated pipeline (empirical
// stats of the same x-hat values, same reduction order), and z here uses
// fp32 x-hat (validated pipeline rounded x through bf16 -> we are strictly
// closer to the reference).
// ---------------------------------------------------------------------------
__global__ __launch_bounds__(512) void fused_gemm_bn_sparsemax(
    const unsigned short* __restrict__ aB,
    const unsigned short* __restrict__ wB,
    const float* __restrict__ bias,
    const float* __restrict__ ps,
    const float* __restrict__ scale,
    const float* __restrict__ shift,
    float* __restrict__ m_out,
    float* __restrict__ ps_out) {
    const int lane = threadIdx.x & 63;
    const int wave = threadIdx.x >> 6;      // 0..7
    const int r16  = lane & 15;
    const int quad = lane >> 4;             // 0..3
    const int row0 = blockIdx.x * 16;
    const int c0   = wave * 256;

    f32x4 acc[16];
    #pragma unroll
    for (int t = 0; t < 16; ++t)
        acc[t] = (f32x4){0.f, 0.f, 0.f, 0.f};

    const unsigned short* aR = aB + (size_t)(row0 + r16) * N_A;   // shared by all waves
    const unsigned short* wR = wB + (size_t)(c0 + r16) * N_A;

    #pragma unroll
    for (int ks = 0; ks < 8; ++ks) {
        const int k0 = ks * 32 + quad * 8;
        short8 a0 = *reinterpret_cast<const short8*>(aR + k0);
        #pragma unroll
        for (int t = 0; t < 16; ++t) {
            short8 bf = *reinterpret_cast<const short8*>(wR + (size_t)t * 16 * N_A + k0);
            acc[t] = __builtin_amdgcn_mfma_f32_16x16x32_bf16(a0, bf, acc[t], 0, 0, 0);
        }
    }

    // phase 2: z = ((x + bias)*scale + shift)*ps in-register; per-row s/max/min
    float sp[4]  = {0.f, 0.f, 0.f, 0.f};
    float mxp[4] = {-INFINITY, -INFINITY, -INFINITY, -INFINITY};
    float mnp[4] = {INFINITY, INFINITY, INFINITY, INFINITY};
    #pragma unroll
    for (int t = 0; t < 16; ++t) {
        const int col = c0 + t * 16 + r16;
        const float bcol = bias[col];
        const float sc   = scale[col];
        const float sh   = shift[col];
        #pragma unroll
        for (int r = 0; r < 4; ++r) {
            const int row = row0 + quad * 4 + r;
            const float p = ps[(size_t)row * N_F + col];
            const float v = acc[t][r] + bcol;
            const float z = (v * sc + sh) * p;
            acc[t][r] = z;
            sp[r]  += z;
            mxp[r]  = fmaxf(mxp[r], z);
            mnp[r]  = fminf(mnp[r], z);
        }
    }
    // reduce across the 16 lanes (r16) of each quad
    #pragma unroll
    for (int off = 1; off < 16; off <<= 1) {
        #pragma unroll
        for (int r = 0; r < 4; ++r) {
            sp[r]  += __shfl_xor(sp[r], off);
            mxp[r]  = fmaxf(mxp[r], __shfl_xor(mxp[r], off));
            mnp[r]  = fminf(mnp[r], __shfl_xor(mnp[r], off));
        }
    }

    __shared__ float red_s[16][8], red_mx[16][8], red_mn[16][8];
    __shared__ float tau_s[16];
    if (r16 == 0) {
        #pragma unroll
        for (int r = 0; r < 4; ++r) {
            red_s[quad * 4 + r][wave]  = sp[r];
            red_mx[quad * 4 + r][wave] = mxp[r];
            red_mn[quad * 4 + r][wave] = mnp[r];
        }
    }
    __syncthreads();
    if (threadIdx.x < 16) {
        float s = 0.f, mx = -INFINITY, mn = INFINITY;
        #pragma unroll
        for (int w = 0; w < 8; ++w) {
            s += red_s[threadIdx.x][w];
            mx = fmaxf(mx, red_mx[threadIdx.x][w]);
            mn = fminf(mn, red_mn[threadIdx.x][w]);
        }
        const float c_last = 1.0f + (float)(N_F - 1) * mx - s;
        tau_s[threadIdx.x] = (c_last > 0.0f) ? (s + 1.0f) / (float)(N_F - 1)
                                             : (mn + 1.0f) / 0.0f;
    }
    __syncthreads();

    // phase 3: outputs (ps re-read hits L2; same values as phase 2)
    #pragma unroll
    for (int t = 0; t < 16; ++t) {
        const int col = c0 + t * 16 + r16;
        #pragma unroll
        for (int r = 0; r < 4; ++r) {
            const int row = row0 + quad * 4 + r;
            const float tau = tau_s[quad * 4 + r];
            const float p   = ps[(size_t)row * N_F + col];
            const float m   = fmaxf(acc[t][r] - tau, 0.f);
            m_out[(size_t)row * N_F + col]  = m;
            ps_out[(size_t)row * N_F + col] = p * (GAMMA - m);
        }
    }
}

// ---------------------------------------------------------------------------
extern "C" void kernel_launch(void* const* d_in, const int* in_sizes, int n_in,
                              void* d_out, int out_size, void* d_ws, size_t ws_size,
                              hipStream_t stream) {
    const float* a    = (const float*)d_in[0];  // [N, 256]
    const float* ps   = (const float*)d_in[1];  // [N, 2048]
    const float* W    = (const float*)d_in[2];  // [2048, 256]
    const float* bias = (const float*)d_in[3];  // [2048]
    const float* bnw  = (const float*)d_in[4];
    const float* bnb  = (const float*)d_in[5];

    float* out    = (float*)d_out;
    float* m_out  = out;
    float* ps_out = out + (size_t)N_ROWS * N_F;

    // Workspace layout: identical footprint to the validated 492 us kernel
    // (11 MB + 16 KB).
    char* ws = (char*)d_ws;
    unsigned short* aB = (unsigned short*)ws;                    // 8 MB
    unsigned short* wB = (unsigned short*)(ws + (8u << 20));     // 1 MB
    float* ps1   = (float*)(ws + (9u  << 20));                   // 1 MB (128x2048)
    float* ps2   = (float*)(ws + (10u << 20));                   // 1 MB
    float* scale = (float*)(ws + (11u << 20));                   // 8 KB
    float* shift = (float*)(ws + (11u << 20) + 8192);            // 8 KB

    cvt_bf16<<<4096, 256, 0, stream>>>(a, aB, N_ROWS * N_A / 4);
    cvt_bf16<<<512, 256, 0, stream>>>(W, wB, N_F * N_A / 4);
    gemm_stats<<<dim3(N_F / 128, N_ROWS / 128), 256, 0, stream>>>(aB, wB, bias, ps1, ps2);
    finalize_stats<<<N_F / 256, 256, 0, stream>>>(ps1, ps2, bnw, bnb, scale, shift);
    fused_gemm_bn_sparsemax<<<N_ROWS / 16, 512, 0, stream>>>(aB, wB, bias, ps, scale,
                                                             shift, m_out, ps_out);
}

// Round 3
// 447.554 us; speedup vs baseline: 1.5995x; 1.5995x over previous
//
#include <hip/hip_runtime.h>
#include <hip/hip_bf16.h>
#include <math.h>

// Problem constants
#define N_ROWS 16384
#define N_A    256
#define N_F    2048
#define GAMMA  1.5f
#define BN_EPS 1e-5f

typedef __attribute__((ext_vector_type(8))) short short8;
typedef __attribute__((ext_vector_type(4))) float f32x4;

// ---------------------------------------------------------------------------
// K0: fp32 -> bf16 conversion (4 elements/thread, vectorized) — validated
// ---------------------------------------------------------------------------
__global__ __launch_bounds__(256) void cvt_bf16(const float* __restrict__ in,
                                                unsigned short* __restrict__ out,
                                                int n4) {
    int i = blockIdx.x * 256 + threadIdx.x;
    if (i >= n4) return;
    float4 v = reinterpret_cast<const float4*>(in)[i];
    ushort4 o;
    o.x = __builtin_bit_cast(unsigned short, __float2bfloat16(v.x));
    o.y = __builtin_bit_cast(unsigned short, __float2bfloat16(v.y));
    o.z = __builtin_bit_cast(unsigned short, __float2bfloat16(v.z));
    o.w = __builtin_bit_cast(unsigned short, __float2bfloat16(v.w));
    reinterpret_cast<ushort4*>(out)[i] = o;
}

// ---------------------------------------------------------------------------
// K1: x = a @ W^T + b — validated round-0 kernel with ONE change: the W tile
// (128 cols x full K=256 = 64 KB, contiguous in global) is staged into LDS
// via global_load_lds width=16 with XOR-swizzled per-lane GLOBAL source
// (LDS dest stays linear — m104/m173 rule). ds_read_b128 fragments then use
// addr = row*512 + ((ks*64 + quad*16) ^ ((row&7)<<4)), which distributes the
// 64 lanes uniformly over the 8x16B bank window (b128 conflict floor) instead
// of the 16-way conflict of the raw 512B row stride. MFMA order, bias add,
// stats reduction, LDS-transpose x store: byte-identical to the validated
// kernel (same numerics, absmax 0.03125 pipeline).
// smem is reused: [staging W 64KB] -> barrier -> [transpose tile 34.8KB].
// ---------------------------------------------------------------------------
__global__ __launch_bounds__(256) void gemm_x(const unsigned short* __restrict__ aB,
                                              const unsigned short* __restrict__ wB,
                                              const float* __restrict__ bias,
                                              unsigned short* __restrict__ xB,
                                              float* __restrict__ ps1,
                                              float* __restrict__ ps2) {
    const int tid  = threadIdx.x;
    const int lane = tid & 63;
    const int wave = tid >> 6;
    const int r16  = lane & 15;
    const int quad = lane >> 4;
    const int col0 = blockIdx.x * 128;
    const int rowB = blockIdx.y * 128;
    const int row0 = rowB + wave * 32;

    __shared__ char smem[65536];   // W tile (swizzled), later reused as transpose tile

    // ---- stage W tile: W rows col0..col0+127, all 256 k (one contiguous 64 KB
    // global block). Chunk c = i*256 + tid is lane-linear within each wave, so
    // the LDS dest is wave-uniform-base + lane*16 (global_load_lds requirement).
    // Swizzle applied on the global source; LDS content = W_row[off ^ sw(row)].
    {
        const char* wsrc = (const char*)(wB + (size_t)col0 * N_A);
        #pragma unroll
        for (int i = 0; i < 16; ++i) {
            const int c   = i * 256 + tid;           // 16B-chunk index (0..4095)
            const int row = c >> 5;                  // 0..127 (32 chunks per 512B row)
            const int off = (c & 31) * 16;           // byte offset within row
            const int src = off ^ ((row & 7) << 4);  // pre-swizzled source offset
            __builtin_amdgcn_global_load_lds(
                (const __attribute__((address_space(1))) void*)(wsrc + (size_t)row * 512 + src),
                (__attribute__((address_space(3))) void*)(smem + c * 16),
                16, 0, 0);
        }
    }

    f32x4 acc[2][8];
    #pragma unroll
    for (int g = 0; g < 2; ++g)
        #pragma unroll
        for (int t = 0; t < 8; ++t)
            acc[g][t] = (f32x4){0.f, 0.f, 0.f, 0.f};

    const unsigned short* aR0 = aB + (size_t)(row0 + r16) * N_A;
    const unsigned short* aR1 = aR0 + 16 * N_A;

    __syncthreads();   // drains vmcnt: staged W visible to all waves

    const int swz = (r16 & 7) << 4;   // row&7 == r16&7 since row = t*16 + r16
    #pragma unroll
    for (int ks = 0; ks < 8; ++ks) {
        const int k0  = ks * 32 + quad * 8;               // A element offset
        short8 a0 = *reinterpret_cast<const short8*>(aR0 + k0);
        short8 a1 = *reinterpret_cast<const short8*>(aR1 + k0);
        const int wof = (ks * 64 + quad * 16) ^ swz;      // swizzled byte-in-row
        #pragma unroll
        for (int t = 0; t < 8; ++t) {
            short8 bf = *reinterpret_cast<const short8*>(
                            smem + (t * 16 + r16) * 512 + wof);
            acc[0][t] = __builtin_amdgcn_mfma_f32_16x16x32_bf16(a0, bf, acc[0][t], 0, 0, 0);
            acc[1][t] = __builtin_amdgcn_mfma_f32_16x16x32_bf16(a1, bf, acc[1][t], 0, 0, 0);
        }
    }

    __syncthreads();   // all waves done reading W before smem is reused as tile

    __shared__ float cs1[4][128];
    __shared__ float cs2[4][128];
    unsigned short (*tile)[136] = (unsigned short (*)[136])smem;  // 128x136x2 = 34.8 KB

    #pragma unroll
    for (int t = 0; t < 8; ++t) {
        const float bcol = bias[col0 + t * 16 + r16];
        float s1 = 0.f, s2 = 0.f;
        #pragma unroll
        for (int g = 0; g < 2; ++g) {
            #pragma unroll
            for (int r = 0; r < 4; ++r) {
                float v = acc[g][t][r] + bcol;
                s1 += v;
                s2 += v * v;
                tile[wave * 32 + g * 16 + quad * 4 + r][t * 16 + r16] =
                    __builtin_bit_cast(unsigned short, __float2bfloat16(v));
            }
        }
        // reduce across the 4 quads (rows) -> per-column sums over 32 rows
        s1 += __shfl_xor(s1, 16); s1 += __shfl_xor(s1, 32);
        s2 += __shfl_xor(s2, 16); s2 += __shfl_xor(s2, 32);
        if (quad == 0) { cs1[wave][t * 16 + r16] = s1; cs2[wave][t * 16 + r16] = s2; }
    }
    __syncthreads();

    if (threadIdx.x < 128) {
        const int c = threadIdx.x;
        float s1 = cs1[0][c] + cs1[1][c] + cs1[2][c] + cs1[3][c];
        float s2 = cs2[0][c] + cs2[1][c] + cs2[2][c] + cs2[3][c];
        ps1[(size_t)blockIdx.y * N_F + col0 + c] = s1;
        ps2[(size_t)blockIdx.y * N_F + col0 + c] = s2;
    }

    // coalesced bf16 tile store: 256 threads x 128 B each
    {
        const int r = threadIdx.x >> 1;
        const int h = threadIdx.x & 1;
        const unsigned short* src = &tile[r][h * 64];
        unsigned short* dst = xB + (size_t)(rowB + r) * 4096 + col0 + h * 64;
        #pragma unroll
        for (int i = 0; i < 8; ++i)
            *reinterpret_cast<short8*>(dst + i * 8) =
                *reinterpret_cast<const short8*>(src + i * 8);
    }
}

// ---------------------------------------------------------------------------
// K2: finalize BN stats (sum 128 deterministic partials) -> scale/shift
// — VERBATIM validated.
// ---------------------------------------------------------------------------
__global__ __launch_bounds__(256) void finalize_stats(const float* __restrict__ ps1,
                                                      const float* __restrict__ ps2,
                                                      const float* __restrict__ bn_w,
                                                      const float* __restrict__ bn_b,
                                                      float* __restrict__ scale,
                                                      float* __restrict__ shift) {
    const int f = blockIdx.x * 256 + threadIdx.x;
    float s1 = 0.f, s2 = 0.f;
    #pragma unroll 4
    for (int i = 0; i < 128; ++i) {
        s1 += ps1[(size_t)i * N_F + f];
        s2 += ps2[(size_t)i * N_F + f];
    }
    const float inv_n = 1.0f / (float)N_ROWS;
    const float mu  = s1 * inv_n;
    const float var = s2 * inv_n - mu * mu;
    const float sc  = bn_w[f] / sqrtf(var + BN_EPS);
    scale[f] = sc;
    shift[f] = bn_b[f] - mu * sc;
}

// ---------------------------------------------------------------------------
// K3: fused BN + sparsemax + prior update. One block (256 thr) per row.
// — VERBATIM validated (round-0, 492 us, absmax 0.03125).
// ---------------------------------------------------------------------------
__global__ __launch_bounds__(256) void bn_sparsemax(const unsigned short* xB,
                                                    const float* __restrict__ ps,
                                                    const float* __restrict__ scale,
                                                    const float* __restrict__ shift,
                                                    float* m_out,
                                                    float* __restrict__ ps_out) {
    const int row = blockIdx.x;
    const int tid = threadIdx.x;
    const int f0  = tid * 8;

    const unsigned short* xr = xB + (size_t)row * 4096 + f0;
    const float* pr = ps + (size_t)row * N_F + f0;

    short8 xv = *reinterpret_cast<const short8*>(xr);
    float4 p0  = *reinterpret_cast<const float4*>(pr);
    float4 p1  = *reinterpret_cast<const float4*>(pr + 4);
    float4 sc0 = *reinterpret_cast<const float4*>(scale + f0);
    float4 sc1 = *reinterpret_cast<const float4*>(scale + f0 + 4);
    float4 sh0 = *reinterpret_cast<const float4*>(shift + f0);
    float4 sh1 = *reinterpret_cast<const float4*>(shift + f0 + 4);

    float pv[8]  = {p0.x, p0.y, p0.z, p0.w, p1.x, p1.y, p1.z, p1.w};
    float scv[8] = {sc0.x, sc0.y, sc0.z, sc0.w, sc1.x, sc1.y, sc1.z, sc1.w};
    float shv[8] = {sh0.x, sh0.y, sh0.z, sh0.w, sh1.x, sh1.y, sh1.z, sh1.w};

    float z[8];
    float s = 0.f, mx = -INFINITY, mn = INFINITY;
    #pragma unroll
    for (int i = 0; i < 8; ++i) {
        float xf = __builtin_bit_cast(float,
                       (unsigned int)((unsigned short)xv[i]) << 16);
        float zz = (xf * scv[i] + shv[i]) * pv[i];
        z[i] = zz;
        s += zz;
        mx = fmaxf(mx, zz);
        mn = fminf(mn, zz);
    }

    // wave (64-lane) butterfly reduction
    #pragma unroll
    for (int off = 32; off > 0; off >>= 1) {
        s  += __shfl_xor(s, off);
        mx  = fmaxf(mx, __shfl_xor(mx, off));
        mn  = fminf(mn, __shfl_xor(mn, off));
    }
    __shared__ float rs[4], rmx[4], rmn[4];
    const int wave = tid >> 6;
    if ((tid & 63) == 0) { rs[wave] = s; rmx[wave] = mx; rmn[wave] = mn; }
    __syncthreads();   // also orders xB reads before the aliased m_out writes
    s  = rs[0] + rs[1] + rs[2] + rs[3];
    mx = fmaxf(fmaxf(rmx[0], rmx[1]), fmaxf(rmx[2], rmx[3]));
    mn = fminf(fminf(rmn[0], rmn[1]), fminf(rmn[2], rmn[3]));

    const float c_last = 1.0f + (float)(N_F - 1) * mx - s;
    float tau;
    if (c_last > 0.0f) {
        tau = (s + 1.0f) / (float)(N_F - 1);
    } else {
        tau = (mn + 1.0f) / 0.0f;   // reference degenerate branch (k_z = 0)
    }

    float* mo = m_out  + (size_t)row * N_F + f0;
    float* po = ps_out + (size_t)row * N_F + f0;
    float4 mv0, mv1, po0, po1;
    mv0.x = fmaxf(z[0] - tau, 0.f); po0.x = pv[0] * (GAMMA - mv0.x);
    mv0.y = fmaxf(z[1] - tau, 0.f); po0.y = pv[1] * (GAMMA - mv0.y);
    mv0.z = fmaxf(z[2] - tau, 0.f); po0.z = pv[2] * (GAMMA - mv0.z);
    mv0.w = fmaxf(z[3] - tau, 0.f); po0.w = pv[3] * (GAMMA - mv0.w);
    mv1.x = fmaxf(z[4] - tau, 0.f); po1.x = pv[4] * (GAMMA - mv1.x);
    mv1.y = fmaxf(z[5] - tau, 0.f); po1.y = pv[5] * (GAMMA - mv1.y);
    mv1.z = fmaxf(z[6] - tau, 0.f); po1.z = pv[6] * (GAMMA - mv1.z);
    mv1.w = fmaxf(z[7] - tau, 0.f); po1.w = pv[7] * (GAMMA - mv1.w);
    *reinterpret_cast<float4*>(mo)     = mv0;
    *reinterpret_cast<float4*>(mo + 4) = mv1;
    *reinterpret_cast<float4*>(po)     = po0;
    *reinterpret_cast<float4*>(po + 4) = po1;
}

// ---------------------------------------------------------------------------
extern "C" void kernel_launch(void* const* d_in, const int* in_sizes, int n_in,
                              void* d_out, int out_size, void* d_ws, size_t ws_size,
                              hipStream_t stream) {
    const float* a    = (const float*)d_in[0];  // [N, 256]
    const float* ps   = (const float*)d_in[1];  // [N, 2048]
    const float* W    = (const float*)d_in[2];  // [2048, 256]
    const float* bias = (const float*)d_in[3];  // [2048]
    const float* bnw  = (const float*)d_in[4];
    const float* bnb  = (const float*)d_in[5];

    float* out    = (float*)d_out;
    float* m_out  = out;
    float* ps_out = out + (size_t)N_ROWS * N_F;
    // bf16 x lives interleaved in the m region: row r occupies the first
    // 4096 B of m-row r (stride 4096 ushorts = 8192 B).
    unsigned short* xB = (unsigned short*)d_out;

    char* ws = (char*)d_ws;
    unsigned short* aB = (unsigned short*)ws;                    // 8 MB
    unsigned short* wB = (unsigned short*)(ws + (8u << 20));     // 1 MB
    float* ps1   = (float*)(ws + (9u  << 20));                   // 1 MB (128x2048)
    float* ps2   = (float*)(ws + (10u << 20));                   // 1 MB
    float* scale = (float*)(ws + (11u << 20));                   // 8 KB
    float* shift = (float*)(ws + (11u << 20) + 8192);            // 8 KB

    cvt_bf16<<<4096, 256, 0, stream>>>(a, aB, N_ROWS * N_A / 4);
    cvt_bf16<<<512, 256, 0, stream>>>(W, wB, N_F * N_A / 4);
    gemm_x<<<dim3(N_F / 128, N_ROWS / 128), 256, 0, stream>>>(aB, wB, bias, xB, ps1, ps2);
    finalize_stats<<<N_F / 256, 256, 0, stream>>>(ps1, ps2, bnw, bnb, scale, shift);
    bn_sparsemax<<<N_ROWS, 256, 0, stream>>>(xB, ps, scale, shift, m_out, ps_out);
}